// Round 3
// baseline (317.518 us; speedup 1.0000x reference)
//
#include <hip/hip_runtime.h>
#include <math.h>

#define BB 64
#define CC 1024
#define QQ 256
#define DD 128
#define NEGV (-1.0e30f)

typedef short bf8 __attribute__((ext_vector_type(8)));
typedef short bf4 __attribute__((ext_vector_type(4)));
typedef float f4v __attribute__((ext_vector_type(4)));

__device__ __forceinline__ short f2bf(float f) {
    unsigned u = __builtin_bit_cast(unsigned, f);
    u += 0x7FFFu + ((u >> 16) & 1u);            // RNE
    return (short)(u >> 16);
}
__device__ __forceinline__ float bf2f(short s) {
    unsigned u = ((unsigned)(unsigned short)s) << 16;
    return __builtin_bit_cast(float, u);
}

// ---------------- k0: fused precompute ----------------
// xc tiles (1024 blocks): s0m = xc@W0 + NEG*(1-cmask); xc_bf row-major; xcT_bf [d][c]
// xq tiles (256 blocks):  s1m = xq@W1 + NEG*(1-qmask); xqw_bf = bf16(xq*W2); xqT_bf [d][q]
__global__ __launch_bounds__(256) void k0_fused(
        const float* __restrict__ xc, const float* __restrict__ xq,
        const float* __restrict__ W0, const float* __restrict__ W1,
        const float* __restrict__ W2,
        const float* __restrict__ c_mask, const float* __restrict__ q_mask,
        float* __restrict__ s0m, float* __restrict__ s1m,
        short* __restrict__ xc_bf, short* __restrict__ xqw_bf,
        short* __restrict__ xcT_bf, short* __restrict__ xqT_bf) {
    __shared__ float tile[64][132];
    int t = threadIdx.x;
    int r = t >> 2, seg = t & 3;          // loader mapping: 64 rows x 4 segs of 32
    int d = t >> 1, half = t & 1;         // transposer mapping: 128 d x 2 halves of 32

    if (blockIdx.x < BB * (CC / 64)) {
        int b = blockIdx.x >> 4, rt = blockIdx.x & 15;
        int row = b * CC + rt * 64 + r;
        const float4* src = (const float4*)(xc + (size_t)row * DD + seg * 32);
        const float4* w0 = (const float4*)(W0 + seg * 32);
        short* dst = xc_bf + (size_t)row * DD + seg * 32;
        float acc = 0.f;
        #pragma unroll
        for (int i = 0; i < 8; i++) {
            float4 v = src[i];
            float4 w = w0[i];
            acc += v.x * w.x + v.y * w.y + v.z * w.z + v.w * w.w;
            bf4 o; o[0] = f2bf(v.x); o[1] = f2bf(v.y); o[2] = f2bf(v.z); o[3] = f2bf(v.w);
            *(bf4*)&dst[i * 4] = o;
            *(float4*)&tile[r][seg * 32 + i * 4] = v;
        }
        acc += __shfl_xor(acc, 1, 64);
        acc += __shfl_xor(acc, 2, 64);
        if (seg == 0) s0m[row] = acc + NEGV * (1.0f - c_mask[row]);
        __syncthreads();
        short* drow = xcT_bf + ((size_t)(b * DD + d)) * CC + rt * 64 + half * 32;
        #pragma unroll
        for (int jj = 0; jj < 4; jj++) {
            bf8 o;
            #pragma unroll
            for (int i = 0; i < 8; i++) o[i] = f2bf(tile[half * 32 + jj * 8 + i][d]);
            *(bf8*)&drow[jj * 8] = o;
        }
    } else {
        int id = blockIdx.x - BB * (CC / 64);
        int b = id >> 2, rt = id & 3;
        int row = b * QQ + rt * 64 + r;
        const float4* src = (const float4*)(xq + (size_t)row * DD + seg * 32);
        const float4* w1 = (const float4*)(W1 + seg * 32);
        const float4* w2 = (const float4*)(W2 + seg * 32);
        short* dst = xqw_bf + (size_t)row * DD + seg * 32;
        float acc = 0.f;
        #pragma unroll
        for (int i = 0; i < 8; i++) {
            float4 v = src[i];
            float4 w = w1[i];
            float4 m = w2[i];
            acc += v.x * w.x + v.y * w.y + v.z * w.z + v.w * w.w;
            bf4 o; o[0] = f2bf(v.x * m.x); o[1] = f2bf(v.y * m.y);
                   o[2] = f2bf(v.z * m.z); o[3] = f2bf(v.w * m.w);
            *(bf4*)&dst[i * 4] = o;
            *(float4*)&tile[r][seg * 32 + i * 4] = v;
        }
        acc += __shfl_xor(acc, 1, 64);
        acc += __shfl_xor(acc, 2, 64);
        if (seg == 0) s1m[row] = acc + NEGV * (1.0f - q_mask[row]);
        __syncthreads();
        short* drow = xqT_bf + ((size_t)(b * DD + d)) * QQ + rt * 64 + half * 32;
        #pragma unroll
        for (int jj = 0; jj < 4; jj++) {
            bf8 o;
            #pragma unroll
            for (int i = 0; i < 8; i++) o[i] = f2bf(tile[half * 32 + jj * 8 + i][d]);
            *(bf8*)&drow[jj * 8] = o;
        }
    }
}

#define SCP 1032   // k1 score row stride (shorts)

// ---------------- k1: col softmax over c, AT[b][d][q] ----------------
// block = (b, 16 q), grid 1024.  3 barriers total; A/B frags from global where per-wave.
__global__ __launch_bounds__(256, 4) void k1_colsm(
        const short* __restrict__ xc_bf, const short* __restrict__ xcT_bf,
        const short* __restrict__ xqw_bf, const float* __restrict__ s0m,
        short* __restrict__ AT) {
    __shared__ __align__(16) short sc[16][SCP];   // 33.0 KB scores
    __shared__ __align__(16) short xqs[16][136];  // 4.3 KB this block's xqw rows
    __shared__ float invl[16];

    int b = blockIdx.x >> 4, qt = blockIdx.x & 15, q0 = qt * 16;
    int t = threadIdx.x, w = t >> 6, l = t & 63;
    int quad = l >> 4, l16 = l & 15;

    {
        int d8 = t & 15, q = t >> 4;
        *(bf8*)&xqs[q][d8 * 8] =
            *(const bf8*)&xqw_bf[((size_t)(b * QQ + q0 + q)) * DD + d8 * 8];
    }
    __syncthreads();

    // ---- phase A: S[c][q] (M=c, N=q, K=d); A-frags straight from global ----
    const short* aBase = xc_bf + ((size_t)(b * CC + w * 16 + l16)) * DD + quad * 8;
    for (int ct = 0; ct < 16; ++ct) {
        f4v acc = {0.f, 0.f, 0.f, 0.f};
        #pragma unroll
        for (int ks = 0; ks < 4; ++ks) {
            bf8 a = *(const bf8*)(aBase + (size_t)ct * 64 * DD + ks * 32);
            bf8 bb = *(const bf8*)&xqs[l16][ks * 32 + quad * 8];
            acc = __builtin_amdgcn_mfma_f32_16x16x32_bf16(a, bb, acc, 0, 0, 0);
        }
        float4 sv = *(const float4*)&s0m[b * CC + ct * 64 + w * 16 + quad * 4];
        bf4 ov;
        ov[0] = f2bf(acc[0] + sv.x); ov[1] = f2bf(acc[1] + sv.y);
        ov[2] = f2bf(acc[2] + sv.z); ov[3] = f2bf(acc[3] + sv.w);
        *(bf4*)&sc[l16][ct * 64 + w * 16 + quad * 4] = ov;
    }
    __syncthreads();

    // ---- phase B: softmax over c per q (vectorized bf8) ----
    {
        int q = t >> 4, k = t & 15;
        float m = -3.0e38f;
        #pragma unroll
        for (int p = 0; p < 8; ++p) {
            bf8 v8 = *(const bf8*)&sc[q][p * 128 + k * 8];
            #pragma unroll
            for (int i = 0; i < 8; ++i) m = fmaxf(m, bf2f(v8[i]));
        }
        #pragma unroll
        for (int off = 1; off < 16; off <<= 1) m = fmaxf(m, __shfl_xor(m, off, 64));
        float sum = 0.f;
        #pragma unroll
        for (int p = 0; p < 8; ++p) {
            bf8 v8 = *(const bf8*)&sc[q][p * 128 + k * 8];
            bf8 e8;
            #pragma unroll
            for (int i = 0; i < 8; ++i) {
                float e = __expf(bf2f(v8[i]) - m);
                e8[i] = f2bf(e);
                sum += e;
            }
            *(bf8*)&sc[q][p * 128 + k * 8] = e8;
        }
        #pragma unroll
        for (int off = 1; off < 16; off <<= 1) sum += __shfl_xor(sum, off, 64);
        if (k == 0) invl[q] = 1.0f / sum;
    }
    __syncthreads();

    // ---- phase C: AT (M=q, N=d, K=c); B-frags straight from global xcT ----
    const short* bBase0 = xcT_bf + ((size_t)(b * DD + w * 32 + l16)) * CC + quad * 8;
    const short* bBase1 = bBase0 + (size_t)16 * CC;
    f4v acc0 = {0.f, 0.f, 0.f, 0.f}, acc1 = {0.f, 0.f, 0.f, 0.f};
    for (int ks = 0; ks < 32; ++ks) {
        bf8 a = *(const bf8*)&sc[l16][ks * 32 + quad * 8];
        bf8 b0 = *(const bf8*)(bBase0 + ks * 32);
        acc0 = __builtin_amdgcn_mfma_f32_16x16x32_bf16(a, b0, acc0, 0, 0, 0);
        bf8 b1 = *(const bf8*)(bBase1 + ks * 32);
        acc1 = __builtin_amdgcn_mfma_f32_16x16x32_bf16(a, b1, acc1, 0, 0, 0);
    }
    {
        bf4 o0, o1;
        #pragma unroll
        for (int r = 0; r < 4; ++r) {
            float il = invl[quad * 4 + r];
            o0[r] = f2bf(acc0[r] * il);
            o1[r] = f2bf(acc1[r] * il);
        }
        int d0 = w * 32 + l16;
        *(bf4*)&AT[((size_t)(b * DD + d0)) * QQ + q0 + quad * 4] = o0;
        *(bf4*)&AT[((size_t)(b * DD + d0 + 16)) * QQ + q0 + quad * 4] = o1;
    }
}

#define S2P 264    // k2 score row stride (shorts)

// ---------------- k2: row softmax over q, c2q/q2c, fused concat ----------------
// block = (b, 32 c), grid 2048.  3 barriers total.
__global__ __launch_bounds__(256, 4) void k2_rowsm(
        const float* __restrict__ xc, const short* __restrict__ xc_bf,
        const short* __restrict__ xqw_bf, const short* __restrict__ xqT_bf,
        const short* __restrict__ AT, const float* __restrict__ s1m,
        float* __restrict__ out) {
    __shared__ __align__(16) short sc2[32][S2P];  // 16.9 KB scores
    __shared__ __align__(16) short xa2[32][136];  // 8.7 KB this block's xc rows
    __shared__ float invl2[32];

    int b = blockIdx.x >> 5, cb = blockIdx.x & 31, c0g = cb * 32;
    int t = threadIdx.x, w = t >> 6, l = t & 63;
    int quad = l >> 4, l16 = l & 15;

    {
        int d8 = t & 15, cr = t >> 4;
        #pragma unroll
        for (int p = 0; p < 2; ++p)
            *(bf8*)&xa2[cr + p * 16][d8 * 8] =
                *(const bf8*)&xc_bf[((size_t)(b * CC + c0g + cr + p * 16)) * DD + d8 * 8];
    }
    __syncthreads();

    // ---- phase 1: S^T (M=q, N=c, K=d); A-frags straight from global xqw ----
    const short* aQ = xqw_bf + ((size_t)(b * QQ + w * 16 + l16)) * DD + quad * 8;
    for (int qt = 0; qt < 4; ++qt) {
        f4v a0 = {0.f, 0.f, 0.f, 0.f}, a1 = {0.f, 0.f, 0.f, 0.f};
        #pragma unroll
        for (int ks = 0; ks < 4; ++ks) {
            bf8 a = *(const bf8*)(aQ + (size_t)qt * 64 * DD + ks * 32);
            bf8 b0 = *(const bf8*)&xa2[l16][ks * 32 + quad * 8];
            a0 = __builtin_amdgcn_mfma_f32_16x16x32_bf16(a, b0, a0, 0, 0, 0);
            bf8 b1 = *(const bf8*)&xa2[16 + l16][ks * 32 + quad * 8];
            a1 = __builtin_amdgcn_mfma_f32_16x16x32_bf16(a, b1, a1, 0, 0, 0);
        }
        int qbase = qt * 64 + w * 16 + quad * 4;
        float4 sv = *(const float4*)&s1m[b * QQ + qbase];
        bf4 o0, o1;
        o0[0] = f2bf(a0[0] + sv.x); o0[1] = f2bf(a0[1] + sv.y);
        o0[2] = f2bf(a0[2] + sv.z); o0[3] = f2bf(a0[3] + sv.w);
        o1[0] = f2bf(a1[0] + sv.x); o1[1] = f2bf(a1[1] + sv.y);
        o1[2] = f2bf(a1[2] + sv.z); o1[3] = f2bf(a1[3] + sv.w);
        *(bf4*)&sc2[l16][qbase] = o0;
        *(bf4*)&sc2[16 + l16][qbase] = o1;
    }
    __syncthreads();

    // ---- phase 2: softmax over q per c (vectorized bf8) ----
    {
        int c = t >> 3, k = t & 7;
        float m = -3.0e38f;
        #pragma unroll
        for (int p = 0; p < 4; ++p) {
            bf8 v8 = *(const bf8*)&sc2[c][p * 64 + k * 8];
            #pragma unroll
            for (int i = 0; i < 8; ++i) m = fmaxf(m, bf2f(v8[i]));
        }
        #pragma unroll
        for (int off = 1; off < 8; off <<= 1) m = fmaxf(m, __shfl_xor(m, off, 64));
        float sum = 0.f;
        #pragma unroll
        for (int p = 0; p < 4; ++p) {
            bf8 v8 = *(const bf8*)&sc2[c][p * 64 + k * 8];
            bf8 e8;
            #pragma unroll
            for (int i = 0; i < 8; ++i) {
                float e = __expf(bf2f(v8[i]) - m);
                e8[i] = f2bf(e);
                sum += e;
            }
            *(bf8*)&sc2[c][p * 64 + k * 8] = e8;
        }
        #pragma unroll
        for (int off = 1; off < 8; off <<= 1) sum += __shfl_xor(sum, off, 64);
        if (k == 0) invl2[c] = 1.0f / sum;
    }
    __syncthreads();

    // ---- phase 3: c2q = W@xq, q2c = W@A (M=c, N=d, K=q); B-frags from global ----
    int cb16 = (w & 1) * 16, dh = (w >> 1) * 64;
    const short* bQ = xqT_bf + ((size_t)(b * DD + dh + l16)) * QQ + quad * 8;
    const short* bA = AT + ((size_t)(b * DD + dh + l16)) * QQ + quad * 8;
    f4v ac[4], aq[4];
    f4v zz = {0.f, 0.f, 0.f, 0.f};
    #pragma unroll
    for (int n = 0; n < 4; ++n) { ac[n] = zz; aq[n] = zz; }
    for (int qs = 0; qs < 8; ++qs) {
        bf8 a = *(const bf8*)&sc2[cb16 + l16][qs * 32 + quad * 8];
        #pragma unroll
        for (int n = 0; n < 4; ++n) {
            bf8 bb = *(const bf8*)(bQ + (size_t)n * 16 * QQ + qs * 32);
            ac[n] = __builtin_amdgcn_mfma_f32_16x16x32_bf16(a, bb, ac[n], 0, 0, 0);
        }
        #pragma unroll
        for (int n = 0; n < 4; ++n) {
            bf8 bb = *(const bf8*)(bA + (size_t)n * 16 * QQ + qs * 32);
            aq[n] = __builtin_amdgcn_mfma_f32_16x16x32_bf16(a, bb, aq[n], 0, 0, 0);
        }
    }

    // ---- epilogue: concat([xc, c2q, xc*c2q, xc*q2c]) ----
    #pragma unroll
    for (int r = 0; r < 4; ++r) {
        int c = c0g + cb16 + quad * 4 + r;
        float il = invl2[cb16 + quad * 4 + r];
        const float* xrow = xc + (size_t)(b * CC + c) * DD;
        float* orow = out + (size_t)(b * CC + c) * (4 * DD);
        #pragma unroll
        for (int n = 0; n < 4; ++n) {
            int d = dh + n * 16 + l16;
            float xv = xrow[d];
            float c2v = ac[n][r] * il;
            float q2v = aq[n][r] * il;
            orow[d] = xv;
            orow[DD + d] = c2v;
            orow[2 * DD + d] = xv * c2v;
            orow[3 * DD + d] = xv * q2v;
        }
    }
}

extern "C" void kernel_launch(void* const* d_in, const int* in_sizes, int n_in,
                              void* d_out, int out_size, void* d_ws, size_t ws_size,
                              hipStream_t stream) {
    const float* x_cont = (const float*)d_in[0];
    const float* x_ques = (const float*)d_in[1];
    const float* c_mask = (const float*)d_in[2];
    const float* q_mask = (const float*)d_in[3];
    const float* W0     = (const float*)d_in[4];
    const float* W1     = (const float*)d_in[5];
    const float* W2     = (const float*)d_in[6];
    // bias cancels in both softmaxes.
    float* out = (float*)d_out;

    char* ws = (char*)d_ws;
    float* s0m    = (float*)ws;  ws += (size_t)BB * CC * 4;
    float* s1m    = (float*)ws;  ws += (size_t)BB * QQ * 4;
    short* xc_bf  = (short*)ws;  ws += (size_t)BB * CC * DD * 2;
    short* xqw_bf = (short*)ws;  ws += (size_t)BB * QQ * DD * 2;
    short* xcT_bf = (short*)ws;  ws += (size_t)BB * CC * DD * 2;
    short* xqT_bf = (short*)ws;  ws += (size_t)BB * QQ * DD * 2;
    short* AT     = (short*)ws;  // B*D*Q

    k0_fused<<<BB * (CC / 64) + BB * (QQ / 64), 256, 0, stream>>>(
        x_cont, x_ques, W0, W1, W2, c_mask, q_mask,
        s0m, s1m, xc_bf, xqw_bf, xcT_bf, xqT_bf);
    k1_colsm<<<BB * 16, 256, 0, stream>>>(xc_bf, xcT_bf, xqw_bf, s0m, AT);
    k2_rowsm<<<BB * 32, 256, 0, stream>>>(x_cont, xc_bf, xqw_bf, xqT_bf, AT, s1m, out);
}